// Round 3
// baseline (2030.243 us; speedup 1.0000x reference)
//
#include <hip/hip_runtime.h>
#include <math.h>

typedef float floatx4 __attribute__((ext_vector_type(4)));
typedef __bf16 bf16x8 __attribute__((ext_vector_type(8)));
typedef unsigned short ushortx8 __attribute__((ext_vector_type(8)));
typedef unsigned short ushortx4 __attribute__((ext_vector_type(4)));
typedef unsigned short ushortx2 __attribute__((ext_vector_type(2)));

typedef unsigned int __attribute__((address_space(1))) as1_uint;
typedef unsigned int __attribute__((address_space(3))) as3_uint;

#define DEV static __device__ __forceinline__

DEV unsigned short f32_bf16(float f) {
  unsigned u = __float_as_uint(f);
  u += 0x7FFFu + ((u >> 16) & 1u);
  return (unsigned short)(u >> 16);
}
DEV float bf16_f32(unsigned short h) { return __uint_as_float(((unsigned)h) << 16); }
DEV float gelu_f(float x) {
  float x3 = x * x * x;
  return 0.5f * x * (1.0f + tanhf(0.79788456080286536f * (x + 0.044715f * x3)));
}
DEV void gload16(const void* g, void* l) {
  __builtin_amdgcn_global_load_lds((const as1_uint*)g, (as3_uint*)l, 16, 0, 0);
}
DEV floatx4 mfma16(ushortx8 a, ushortx8 b, floatx4 c) {
  return __builtin_amdgcn_mfma_f32_16x16x32_bf16(
      __builtin_bit_cast(bf16x8, a), __builtin_bit_cast(bf16x8, b), c, 0, 0, 0);
}

// ---------------- small kernels ----------------

__global__ void zero_f(float* p, int n) {
  int i = threadIdx.x;
  if (i < n) p[i] = 0.f;
}

__global__ void cvt_f32_bf16(const float* __restrict__ in, unsigned short* __restrict__ out,
                             long n4) {
  long i = (long)blockIdx.x * blockDim.x + threadIdx.x;
  if (i >= n4) return;
  float4 v = ((const float4*)in)[i];
  ushortx4 o;
  o.x = f32_bf16(v.x); o.y = f32_bf16(v.y); o.z = f32_bf16(v.z); o.w = f32_bf16(v.w);
  ((ushortx4*)out)[i] = o;
}

// out[n*2048+k] = in[n*8192 + cbase + k], n<2048, k<2048  (proj_w column slice)
__global__ void cvt_cols(const float* __restrict__ in, unsigned short* __restrict__ out,
                         int cbase) {
  long i = (long)blockIdx.x * blockDim.x + threadIdx.x;  // 1,048,576 float4s
  if (i >= 1048576) return;
  int n = (int)(i >> 9);
  int k4 = (int)(i & 511) << 2;
  float4 v = *(const float4*)&in[(size_t)n * 8192 + cbase + k4];
  ushortx4 o;
  o.x = f32_bf16(v.x); o.y = f32_bf16(v.y); o.z = f32_bf16(v.z); o.w = f32_bf16(v.w);
  *(ushortx4*)&out[(size_t)n * 2048 + k4] = o;
}

// spart[(ks*64+bh)*16384 + d*128 + e] = sum_{s in split ks (512 rows)} Q[b,s,h,d]*K[b,s,h,e]
__global__ __launch_bounds__(256) void attn_scores(const unsigned short* __restrict__ qkv,
                                                   float* __restrict__ spart) {
  int bh = blockIdx.x;
  int b = bh >> 4, h = bh & 15;
  int ks = blockIdx.y;
  __shared__ unsigned short Qc[32 * 128];
  __shared__ unsigned short Kc[32 * 128];
  int tid = threadIdx.x;
  int d0 = (tid >> 4) * 8;
  int e0 = (tid & 15) * 8;
  // staging: 256 threads cover 2 matrices x 32 rows x 128 cols (4 uint4 each)
  int lrow = tid >> 4;         // 0..15
  int lcol = (tid & 15) * 8;   // 0..120
  const unsigned short* qbase = qkv + (size_t)b * 2048 * 6144 + (size_t)h * 128;
  float acc[8][8];
#pragma unroll
  for (int i = 0; i < 8; i++)
#pragma unroll
    for (int j = 0; j < 8; j++) acc[i][j] = 0.f;

  for (int sc = 0; sc < 16; ++sc) {
    int sbase = ks * 512 + sc * 32;
    __syncthreads();
    const unsigned short* src = qbase + (size_t)(sbase + lrow) * 6144 + lcol;
    const unsigned short* src2 = src + (size_t)16 * 6144;
    *(uint4*)&Qc[lrow * 128 + lcol] = *(const uint4*)src;
    *(uint4*)&Kc[lrow * 128 + lcol] = *(const uint4*)(src + 2048);
    *(uint4*)&Qc[(lrow + 16) * 128 + lcol] = *(const uint4*)src2;
    *(uint4*)&Kc[(lrow + 16) * 128 + lcol] = *(const uint4*)(src2 + 2048);
    __syncthreads();
    for (int s = 0; s < 32; ++s) {
      ushortx8 qv = *(const ushortx8*)&Qc[s * 128 + d0];
      ushortx8 kv = *(const ushortx8*)&Kc[s * 128 + e0];
      float q[8], k[8];
#pragma unroll
      for (int i = 0; i < 8; i++) { q[i] = bf16_f32(qv[i]); k[i] = bf16_f32(kv[i]); }
#pragma unroll
      for (int i = 0; i < 8; i++)
#pragma unroll
        for (int j = 0; j < 8; j++) acc[i][j] = fmaf(q[i], k[j], acc[i][j]);
    }
  }
  float* outp = spart + ((size_t)ks * 64 + bh) * 16384;
#pragma unroll
  for (int i = 0; i < 8; i++)
#pragma unroll
    for (int j = 0; j < 8; j++) outp[(d0 + i) * 128 + e0 + j] = acc[i][j];
}

// one wave per row of 128; sums 4 split partials, scales by 1/sqrt(S), softmax, bf16 out
__global__ __launch_bounds__(256) void softmax_k(const float* __restrict__ spart,
                                                 unsigned short* __restrict__ probs) {
  int r = blockIdx.x * 4 + (threadIdx.x >> 6);
  int lane = threadIdx.x & 63;
  size_t base = (size_t)(r >> 7) * 16384 + (size_t)(r & 127) * 128;
  int e0 = lane * 2;
  float vx = 0.f, vy = 0.f;
#pragma unroll
  for (int ks = 0; ks < 4; ++ks) {
    float2 p = *(const float2*)&spart[(size_t)ks * 1048576 + base + e0];
    vx += p.x; vy += p.y;
  }
  const float scale = 0.022097086912079608f;  // 1/sqrt(2048)
  vx *= scale; vy *= scale;
  float m = fmaxf(vx, vy);
#pragma unroll
  for (int off = 32; off; off >>= 1) m = fmaxf(m, __shfl_xor(m, off));
  float ex = expf(vx - m), ey = expf(vy - m);
  float s = ex + ey;
#pragma unroll
  for (int off = 32; off; off >>= 1) s += __shfl_xor(s, off);
  float inv = 1.f / s;
  ushortx2 o;
  o.x = f32_bf16(ex * inv);
  o.y = f32_bf16(ey * inv);
  *(ushortx2*)&probs[base + e0] = o;
}

// global layernorm apply: out = (r - mean)*rstd*w[col] + b[col]
__global__ void ln_apply(const float* __restrict__ r, const float* __restrict__ stats,
                         const float* __restrict__ w, const float* __restrict__ bia,
                         float* __restrict__ outF, unsigned short* __restrict__ outB, long n4) {
  long i = (long)blockIdx.x * blockDim.x + threadIdx.x;
  if (i >= n4) return;
  const double total = 16777216.0;
  double mean = (double)stats[0] / total;
  double var = ((double)stats[1] - total * mean * mean) / (total - 1.0);
  float rstd = (float)(1.0 / sqrt(var + 1e-12));
  float fm = (float)mean;
  int col = (int)((i * 4) & 2047);
  float4 v = ((const float4*)r)[i];
  float4 wv = *(const float4*)&w[col];
  float4 bv = *(const float4*)&bia[col];
  float4 o;
  o.x = (v.x - fm) * rstd * wv.x + bv.x;
  o.y = (v.y - fm) * rstd * wv.y + bv.y;
  o.z = (v.z - fm) * rstd * wv.z + bv.z;
  o.w = (v.w - fm) * rstd * wv.w + bv.w;
  if (outF) ((float4*)outF)[i] = o;
  if (outB) {
    ushortx4 ob;
    ob.x = f32_bf16(o.x); ob.y = f32_bf16(o.y); ob.z = f32_bf16(o.z); ob.w = f32_bf16(o.w);
    ((ushortx4*)outB)[i] = ob;
  }
}

// ---------------- main GEMM: C[M,N] = A[M,K] @ B[N,K]^T, fused epilogue ----------------
// m97 structure: 128x128 tile, BK=64, global_load_lds width-16 staging,
// 4 waves x 4x4 16x16x32 MFMA. C/D layout: col=lane&15, row=quad*4+reg.
__global__ __launch_bounds__(256) void gemm_bt(
    const unsigned short* __restrict__ A, int lda, long sAo, long sAi,
    const unsigned short* __restrict__ B, int ldb, long sBo, long sBi,
    int K, int innerCnt,
    const float* __restrict__ bias, const float* __restrict__ residF,
    const unsigned short* __restrict__ residB, int accum,
    float* __restrict__ outF, unsigned short* __restrict__ outB,
    int ldc, long sCo, long sCi, int doGelu, float* __restrict__ stats) {
  __shared__ unsigned short As[128 * 64];
  __shared__ unsigned short Bs[128 * 64];
  const int tid = threadIdx.x;
  const int wave = tid >> 6;
  const int lane = tid & 63;
  const int z = blockIdx.z;
  const int zo = z / innerCnt, zi = z % innerCnt;
  const unsigned short* Ab = A + zo * sAo + zi * sAi;
  const unsigned short* Bb = B + zo * sBo + zi * sBi;
  const long coff = zo * sCo + zi * sCi;
  const int m0 = blockIdx.y * 128;
  const int n0 = blockIdx.x * 128;

  const int quad = lane >> 4;
  const int l16 = lane & 15;
  const int wm = (wave & 1) * 64;
  const int wn = (wave >> 1) * 64;
  const int srow = lane >> 3;        // 0..7 within 8-row group
  const int kofs8 = (lane & 7) * 8;  // 0..56

  floatx4 acc[4][4];
#pragma unroll
  for (int i = 0; i < 4; i++)
#pragma unroll
    for (int j = 0; j < 4; j++) acc[i][j] = (floatx4){0.f, 0.f, 0.f, 0.f};

  const int nK = K >> 6;
  for (int kt = 0; kt < nK; ++kt) {
    const int k0 = kt << 6;
    __syncthreads();
#pragma unroll
    for (int i = 0; i < 4; ++i) {
      const int rb = wave * 32 + i * 8;
      gload16(Ab + (size_t)(m0 + rb + srow) * lda + k0 + kofs8, &As[rb * 64]);
      gload16(Bb + (size_t)(n0 + rb + srow) * ldb + k0 + kofs8, &Bs[rb * 64]);
    }
    __syncthreads();
#pragma unroll
    for (int kk = 0; kk < 2; ++kk) {
      ushortx8 af[4], bf[4];
#pragma unroll
      for (int i = 0; i < 4; i++)
        af[i] = *(const ushortx8*)&As[(wm + i * 16 + l16) * 64 + kk * 32 + quad * 8];
#pragma unroll
      for (int j = 0; j < 4; j++)
        bf[j] = *(const ushortx8*)&Bs[(wn + j * 16 + l16) * 64 + kk * 32 + quad * 8];
#pragma unroll
      for (int i = 0; i < 4; i++)
#pragma unroll
        for (int j = 0; j < 4; j++) acc[i][j] = mfma16(af[i], bf[j], acc[i][j]);
    }
  }

  float s1 = 0.f, s2 = 0.f;
#pragma unroll
  for (int i = 0; i < 4; i++) {
#pragma unroll
    for (int j = 0; j < 4; j++) {
      const int col = n0 + wn + j * 16 + l16;
      const float bv = bias ? bias[col] : 0.f;
#pragma unroll
      for (int r = 0; r < 4; r++) {
        const int row = m0 + wm + i * 16 + quad * 4 + r;
        float v = acc[i][j][r] + bv;
        if (doGelu) v = gelu_f(v);
        const size_t cidx = (size_t)coff + (size_t)row * ldc + col;
        if (residF) v += residF[cidx];
        if (residB) v += bf16_f32(residB[cidx]);
        if (accum) v += outF[cidx];
        if (outF) outF[cidx] = v;
        else outB[cidx] = f32_bf16(v);
        if (stats) { s1 += v; s2 += v * v; }
      }
    }
  }
  if (stats) {
#pragma unroll
    for (int off = 32; off; off >>= 1) {
      s1 += __shfl_down(s1, off);
      s2 += __shfl_down(s2, off);
    }
    if (lane == 0) {
      atomicAdd(&stats[0], s1);
      atomicAdd(&stats[1], s2);
    }
  }
}

// ---------------- launch ----------------
// Workspace budget: 152 MB total (region lifetimes overlapped):
//   P0 32MB: xbf -> attnbf -> hchunk
//   P1 24MB: W1bf -> {spart(16)+probs(2)} -> W2bf(8) -> {fc_ch(8)+pj_ch(8)}
//   P2 96MB: qkv -> {r1/r2 fp32(64) + x1bf(32)}

extern "C" void kernel_launch(void* const* d_in, const int* in_sizes, int n_in, void* d_out,
                              int out_size, void* d_ws, size_t ws_size, hipStream_t stream) {
  (void)in_sizes; (void)n_in; (void)out_size; (void)ws_size;
  const float* x    = (const float*)d_in[0];
  const float* W1w  = (const float*)d_in[1];
  const float* W1b  = (const float*)d_in[2];
  const float* W2w  = (const float*)d_in[3];
  const float* W2b  = (const float*)d_in[4];
  const float* fcw  = (const float*)d_in[5];
  const float* fcb  = (const float*)d_in[6];
  const float* pjw  = (const float*)d_in[7];
  const float* pjb  = (const float*)d_in[8];
  const float* ln1w = (const float*)d_in[9];
  const float* ln1b = (const float*)d_in[10];
  const float* ln2w = (const float*)d_in[11];
  const float* ln2b = (const float*)d_in[12];
  float* out = (float*)d_out;

  char* ws = (char*)d_ws;
  size_t off = 0;
  auto take = [&](size_t b) { size_t r = off; off = (off + b + 255) & ~(size_t)255; return r; };
  float* stats = (float*)(ws + take(256));
  size_t P0 = take(33554432);
  size_t P1 = take(25165824);
  size_t P2 = take(100663296);

  unsigned short* xbf    = (unsigned short*)(ws + P0);
  unsigned short* attnbf = (unsigned short*)(ws + P0);
  unsigned short* hchunk = (unsigned short*)(ws + P0);
  unsigned short* W1bf   = (unsigned short*)(ws + P1);
  float*          spart  = (float*)(ws + P1);
  unsigned short* probs  = (unsigned short*)(ws + P1 + 16777216);
  unsigned short* W2bf   = (unsigned short*)(ws + P1);
  unsigned short* fc_ch  = (unsigned short*)(ws + P1);
  unsigned short* pj_ch  = (unsigned short*)(ws + P1 + 8388608);
  unsigned short* qkv    = (unsigned short*)(ws + P2);
  float*          r12    = (float*)(ws + P2);
  unsigned short* x1bf   = (unsigned short*)(ws + P2 + 67108864);

  zero_f<<<1, 64, 0, stream>>>(stats, 16);
  cvt_f32_bf16<<<16384, 256, 0, stream>>>(x, xbf, 4194304);
  cvt_f32_bf16<<<12288, 256, 0, stream>>>(W1w, W1bf, 3145728);

  // QKV: [8192,2048] @ [6144,2048]^T + W1_b -> qkv bf16 [8192,6144]
  gemm_bt<<<dim3(48, 64, 1), 256, 0, stream>>>(xbf, 2048, 0, 0, W1bf, 2048, 0, 0, 2048, 1, W1b,
                                               nullptr, nullptr, 0, nullptr, qkv, 6144, 0, 0, 0,
                                               nullptr);
  // feature-dim attention scores (split over S into 4) + softmax
  attn_scores<<<dim3(64, 4), 256, 0, stream>>>(qkv, spart);
  softmax_k<<<2048, 256, 0, stream>>>(spart, probs);
  // PV per (b,h): [128,128] @ [2048,128]^T -> attn2d[b, h*128+d, s] bf16
  gemm_bt<<<dim3(16, 1, 64), 256, 0, stream>>>(probs, 128, 262144L, 16384L, qkv + 4096, 6144,
                                               12582912L, 128L, 128, 16, nullptr, nullptr, nullptr,
                                               0, nullptr, attnbf, 2048, 4194304L, 262144L, 0,
                                               nullptr);
  // W2 weights (spart dead; probs at P1+16MB untouched)
  cvt_f32_bf16<<<4096, 256, 0, stream>>>(W2w, W2bf, 1048576);
  // W2 + bias + residual(x fp32) -> r1 fp32, stats[0:2]
  gemm_bt<<<dim3(16, 64, 1), 256, 0, stream>>>(attnbf, 2048, 0, 0, W2bf, 2048, 0, 0, 2048, 1, W2b,
                                               x, nullptr, 0, r12, nullptr, 2048, 0, 0, 0, stats);
  ln_apply<<<16384, 256, 0, stream>>>(r12, stats, ln1w, ln1b, nullptr, x1bf, 4194304);

  // FFN in 4 chunks of DFF=2048: h = gelu(x1 @ fc_ch^T + fcb_ch); r2 += h @ pj_ch^T
  for (int c = 0; c < 4; ++c) {
    cvt_f32_bf16<<<4096, 256, 0, stream>>>(fcw + (size_t)c * 4194304, fc_ch, 1048576);
    cvt_cols<<<4096, 256, 0, stream>>>(pjw, pj_ch, c * 2048);
    gemm_bt<<<dim3(16, 64, 1), 256, 0, stream>>>(x1bf, 2048, 0, 0, fc_ch, 2048, 0, 0, 2048, 1,
                                                 fcb + c * 2048, nullptr, nullptr, 0, nullptr,
                                                 hchunk, 2048, 0, 0, 1, nullptr);
    const int last = (c == 3);
    gemm_bt<<<dim3(16, 64, 1), 256, 0, stream>>>(hchunk, 2048, 0, 0, pj_ch, 2048, 0, 0, 2048, 1,
                                                 last ? pjb : nullptr, nullptr,
                                                 last ? x1bf : nullptr, c > 0, r12, nullptr, 2048,
                                                 0, 0, 0, last ? (stats + 2) : nullptr);
  }
  ln_apply<<<16384, 256, 0, stream>>>(r12, stats + 2, ln2w, ln2b, out, nullptr, 4194304);
}

// Round 4
// 1865.417 us; speedup vs baseline: 1.0884x; 1.0884x over previous
//
#include <hip/hip_runtime.h>
#include <math.h>

typedef float floatx4 __attribute__((ext_vector_type(4)));
typedef __bf16 bf16x8 __attribute__((ext_vector_type(8)));
typedef unsigned short ushortx8 __attribute__((ext_vector_type(8)));
typedef unsigned short ushortx4 __attribute__((ext_vector_type(4)));
typedef unsigned short ushortx2 __attribute__((ext_vector_type(2)));

typedef unsigned int __attribute__((address_space(1))) as1_uint;
typedef unsigned int __attribute__((address_space(3))) as3_uint;

#define DEV static __device__ __forceinline__

DEV unsigned short f32_bf16(float f) {
  unsigned u = __float_as_uint(f);
  u += 0x7FFFu + ((u >> 16) & 1u);
  return (unsigned short)(u >> 16);
}
DEV float bf16_f32(unsigned short h) { return __uint_as_float(((unsigned)h) << 16); }
DEV float gelu_f(float x) {
  float x3 = x * x * x;
  return 0.5f * x * (1.0f + tanhf(0.79788456080286536f * (x + 0.044715f * x3)));
}
DEV void gload16(const void* g, void* l) {
  __builtin_amdgcn_global_load_lds((const as1_uint*)g, (as3_uint*)l, 16, 0, 0);
}
DEV floatx4 mfma16(ushortx8 a, ushortx8 b, floatx4 c) {
  return __builtin_amdgcn_mfma_f32_16x16x32_bf16(
      __builtin_bit_cast(bf16x8, a), __builtin_bit_cast(bf16x8, b), c, 0, 0, 0);
}

// ---------------- small kernels ----------------

__global__ void zero_f(float* p, int n) {
  int i = threadIdx.x;
  if (i < n) p[i] = 0.f;
}

__global__ void cvt_f32_bf16(const float* __restrict__ in, unsigned short* __restrict__ out,
                             long n4) {
  long i = (long)blockIdx.x * blockDim.x + threadIdx.x;
  if (i >= n4) return;
  float4 v = ((const float4*)in)[i];
  ushortx4 o;
  o.x = f32_bf16(v.x); o.y = f32_bf16(v.y); o.z = f32_bf16(v.z); o.w = f32_bf16(v.w);
  ((ushortx4*)out)[i] = o;
}

// out[n*2048+k] = in[n*8192 + cbase + k], n<2048, k<2048  (proj_w column slice)
__global__ void cvt_cols(const float* __restrict__ in, unsigned short* __restrict__ out,
                         int cbase) {
  long i = (long)blockIdx.x * blockDim.x + threadIdx.x;  // 1,048,576 float4s
  if (i >= 1048576) return;
  int n = (int)(i >> 9);
  int k4 = (int)(i & 511) << 2;
  float4 v = *(const float4*)&in[(size_t)n * 8192 + cbase + k4];
  ushortx4 o;
  o.x = f32_bf16(v.x); o.y = f32_bf16(v.y); o.z = f32_bf16(v.z); o.w = f32_bf16(v.w);
  *(ushortx4*)&out[(size_t)n * 2048 + k4] = o;
}

// spart[(ks*64+bh)*16384 + d*128 + e] = sum_{s in split ks (512 rows)} Q[b,s,h,d]*K[b,s,h,e]
__global__ __launch_bounds__(256) void attn_scores(const unsigned short* __restrict__ qkv,
                                                   float* __restrict__ spart) {
  int bh = blockIdx.x;
  int b = bh >> 4, h = bh & 15;
  int ks = blockIdx.y;
  __shared__ unsigned short Qc[32 * 128];
  __shared__ unsigned short Kc[32 * 128];
  int tid = threadIdx.x;
  int d0 = (tid >> 4) * 8;
  int e0 = (tid & 15) * 8;
  // staging: 256 threads cover 2 matrices x 32 rows x 128 cols (4 uint4 each)
  int lrow = tid >> 4;         // 0..15
  int lcol = (tid & 15) * 8;   // 0..120
  const unsigned short* qbase = qkv + (size_t)b * 2048 * 6144 + (size_t)h * 128;
  float acc[8][8];
#pragma unroll
  for (int i = 0; i < 8; i++)
#pragma unroll
    for (int j = 0; j < 8; j++) acc[i][j] = 0.f;

  for (int sc = 0; sc < 16; ++sc) {
    int sbase = ks * 512 + sc * 32;
    __syncthreads();
    const unsigned short* src = qbase + (size_t)(sbase + lrow) * 6144 + lcol;
    const unsigned short* src2 = src + (size_t)16 * 6144;
    *(uint4*)&Qc[lrow * 128 + lcol] = *(const uint4*)src;
    *(uint4*)&Kc[lrow * 128 + lcol] = *(const uint4*)(src + 2048);
    *(uint4*)&Qc[(lrow + 16) * 128 + lcol] = *(const uint4*)src2;
    *(uint4*)&Kc[(lrow + 16) * 128 + lcol] = *(const uint4*)(src2 + 2048);
    __syncthreads();
    for (int s = 0; s < 32; ++s) {
      ushortx8 qv = *(const ushortx8*)&Qc[s * 128 + d0];
      ushortx8 kv = *(const ushortx8*)&Kc[s * 128 + e0];
      float q[8], k[8];
#pragma unroll
      for (int i = 0; i < 8; i++) { q[i] = bf16_f32(qv[i]); k[i] = bf16_f32(kv[i]); }
#pragma unroll
      for (int i = 0; i < 8; i++)
#pragma unroll
        for (int j = 0; j < 8; j++) acc[i][j] = fmaf(q[i], k[j], acc[i][j]);
    }
  }
  float* outp = spart + ((size_t)ks * 64 + bh) * 16384;
#pragma unroll
  for (int i = 0; i < 8; i++)
#pragma unroll
    for (int j = 0; j < 8; j++) outp[(d0 + i) * 128 + e0 + j] = acc[i][j];
}

// one wave per row of 128; sums 4 split partials, scales by 1/sqrt(S), softmax, bf16 out
__global__ __launch_bounds__(256) void softmax_k(const float* __restrict__ spart,
                                                 unsigned short* __restrict__ probs) {
  int r = blockIdx.x * 4 + (threadIdx.x >> 6);
  int lane = threadIdx.x & 63;
  size_t base = (size_t)(r >> 7) * 16384 + (size_t)(r & 127) * 128;
  int e0 = lane * 2;
  float vx = 0.f, vy = 0.f;
#pragma unroll
  for (int ks = 0; ks < 4; ++ks) {
    float2 p = *(const float2*)&spart[(size_t)ks * 1048576 + base + e0];
    vx += p.x; vy += p.y;
  }
  const float scale = 0.022097086912079608f;  // 1/sqrt(2048)
  vx *= scale; vy *= scale;
  float m = fmaxf(vx, vy);
#pragma unroll
  for (int off = 32; off; off >>= 1) m = fmaxf(m, __shfl_xor(m, off));
  float ex = expf(vx - m), ey = expf(vy - m);
  float s = ex + ey;
#pragma unroll
  for (int off = 32; off; off >>= 1) s += __shfl_xor(s, off);
  float inv = 1.f / s;
  ushortx2 o;
  o.x = f32_bf16(ex * inv);
  o.y = f32_bf16(ey * inv);
  *(ushortx2*)&probs[base + e0] = o;
}

// global layernorm apply: out = (r - mean)*rstd*w[col] + b[col]
__global__ void ln_apply(const float* __restrict__ r, const float* __restrict__ stats,
                         const float* __restrict__ w, const float* __restrict__ bia,
                         float* __restrict__ outF, unsigned short* __restrict__ outB, long n4) {
  long i = (long)blockIdx.x * blockDim.x + threadIdx.x;
  if (i >= n4) return;
  const double total = 16777216.0;
  double mean = (double)stats[0] / total;
  double var = ((double)stats[1] - total * mean * mean) / (total - 1.0);
  float rstd = (float)(1.0 / sqrt(var + 1e-12));
  float fm = (float)mean;
  int col = (int)((i * 4) & 2047);
  float4 v = ((const float4*)r)[i];
  float4 wv = *(const float4*)&w[col];
  float4 bv = *(const float4*)&bia[col];
  float4 o;
  o.x = (v.x - fm) * rstd * wv.x + bv.x;
  o.y = (v.y - fm) * rstd * wv.y + bv.y;
  o.z = (v.z - fm) * rstd * wv.z + bv.z;
  o.w = (v.w - fm) * rstd * wv.w + bv.w;
  if (outF) ((float4*)outF)[i] = o;
  if (outB) {
    ushortx4 ob;
    ob.x = f32_bf16(o.x); ob.y = f32_bf16(o.y); ob.z = f32_bf16(o.z); ob.w = f32_bf16(o.w);
    ((ushortx4*)outB)[i] = ob;
  }
}

// ---------------- main GEMM: C[M,N] = A[M,K] @ B[N,K]^T, fused epilogue ----------------
// m97 structure: 128x128 tile, BK=64, global_load_lds width-16 staging,
// 4 waves x 4x4 16x16x32 MFMA. C/D layout: col=lane&15, row=quad*4+reg.
// LDS XOR swizzle: physical 16B-slot = logical k-slot ^ (row&7). Rows are 128 B
// (exactly 32 banks) so bank = f(slot) only; the swizzle spreads each quad's
// 16 lanes across all 8 slots -> 2 lanes/slot (free 2-way, m136).
__global__ __launch_bounds__(256) void gemm_bt(
    const unsigned short* __restrict__ A, int lda, long sAo, long sAi,
    const unsigned short* __restrict__ B, int ldb, long sBo, long sBi,
    int K, int innerCnt,
    const float* __restrict__ bias, const float* __restrict__ residF,
    const unsigned short* __restrict__ residB, int accum,
    float* __restrict__ outF, unsigned short* __restrict__ outB,
    int ldc, long sCo, long sCi, int doGelu, float* __restrict__ stats) {
  __shared__ unsigned short As[128 * 64];
  __shared__ unsigned short Bs[128 * 64];
  const int tid = threadIdx.x;
  const int wave = tid >> 6;
  const int lane = tid & 63;
  const int z = blockIdx.z;
  const int zo = z / innerCnt, zi = z % innerCnt;
  const unsigned short* Ab = A + zo * sAo + zi * sAi;
  const unsigned short* Bb = B + zo * sBo + zi * sBi;
  const long coff = zo * sCo + zi * sCi;
  const int m0 = blockIdx.y * 128;
  const int n0 = blockIdx.x * 128;

  const int quad = lane >> 4;
  const int l16 = lane & 15;
  const int wm = (wave & 1) * 64;
  const int wn = (wave >> 1) * 64;
  const int srow = lane >> 3;                          // 0..7 within 8-row group
  const int kofs8 = (((lane & 7) ^ srow) & 7) * 8;     // swizzled k-slot source

  floatx4 acc[4][4];
#pragma unroll
  for (int i = 0; i < 4; i++)
#pragma unroll
    for (int j = 0; j < 4; j++) acc[i][j] = (floatx4){0.f, 0.f, 0.f, 0.f};

  const int nK = K >> 6;
  for (int kt = 0; kt < nK; ++kt) {
    const int k0 = kt << 6;
    __syncthreads();
#pragma unroll
    for (int i = 0; i < 4; ++i) {
      const int rb = wave * 32 + i * 8;
      gload16(Ab + (size_t)(m0 + rb + srow) * lda + k0 + kofs8, &As[rb * 64]);
      gload16(Bb + (size_t)(n0 + rb + srow) * ldb + k0 + kofs8, &Bs[rb * 64]);
    }
    __syncthreads();
#pragma unroll
    for (int kk = 0; kk < 2; ++kk) {
      ushortx8 af[4], bf[4];
      const int swz = (l16 & 7);
#pragma unroll
      for (int i = 0; i < 4; i++)
        af[i] = *(const ushortx8*)&As[(wm + i * 16 + l16) * 64 +
                                      (((kk * 4 + quad) ^ swz) * 8)];
#pragma unroll
      for (int j = 0; j < 4; j++)
        bf[j] = *(const ushortx8*)&Bs[(wn + j * 16 + l16) * 64 +
                                      (((kk * 4 + quad) ^ swz) * 8)];
#pragma unroll
      for (int i = 0; i < 4; i++)
#pragma unroll
        for (int j = 0; j < 4; j++) acc[i][j] = mfma16(af[i], bf[j], acc[i][j]);
    }
  }

  float s1 = 0.f, s2 = 0.f;
#pragma unroll
  for (int i = 0; i < 4; i++) {
#pragma unroll
    for (int j = 0; j < 4; j++) {
      const int col = n0 + wn + j * 16 + l16;
      const float bv = bias ? bias[col] : 0.f;
#pragma unroll
      for (int r = 0; r < 4; r++) {
        const int row = m0 + wm + i * 16 + quad * 4 + r;
        float v = acc[i][j][r] + bv;
        if (doGelu) v = gelu_f(v);
        const size_t cidx = (size_t)coff + (size_t)row * ldc + col;
        if (residF) v += residF[cidx];
        if (residB) v += bf16_f32(residB[cidx]);
        if (accum) v += outF[cidx];
        if (outF) outF[cidx] = v;
        else outB[cidx] = f32_bf16(v);
        if (stats) { s1 += v; s2 += v * v; }
      }
    }
  }
  if (stats) {
#pragma unroll
    for (int off = 32; off; off >>= 1) {
      s1 += __shfl_down(s1, off);
      s2 += __shfl_down(s2, off);
    }
    if (lane == 0) {
      atomicAdd(&stats[0], s1);
      atomicAdd(&stats[1], s2);
    }
  }
}

// ---------------- launch ----------------
// Workspace budget: 152 MB total (region lifetimes overlapped):
//   P0 32MB: xbf -> attnbf -> hchunk
//   P1 24MB: W1bf -> {spart(16)+probs(2)} -> W2bf(8) -> {fc_ch(8)+pj_ch(8)}
//   P2 96MB: qkv -> {r1/r2 fp32(64) + x1bf(32)}

extern "C" void kernel_launch(void* const* d_in, const int* in_sizes, int n_in, void* d_out,
                              int out_size, void* d_ws, size_t ws_size, hipStream_t stream) {
  (void)in_sizes; (void)n_in; (void)out_size; (void)ws_size;
  const float* x    = (const float*)d_in[0];
  const float* W1w  = (const float*)d_in[1];
  const float* W1b  = (const float*)d_in[2];
  const float* W2w  = (const float*)d_in[3];
  const float* W2b  = (const float*)d_in[4];
  const float* fcw  = (const float*)d_in[5];
  const float* fcb  = (const float*)d_in[6];
  const float* pjw  = (const float*)d_in[7];
  const float* pjb  = (const float*)d_in[8];
  const float* ln1w = (const float*)d_in[9];
  const float* ln1b = (const float*)d_in[10];
  const float* ln2w = (const float*)d_in[11];
  const float* ln2b = (const float*)d_in[12];
  float* out = (float*)d_out;

  char* ws = (char*)d_ws;
  size_t off = 0;
  auto take = [&](size_t b) { size_t r = off; off = (off + b + 255) & ~(size_t)255; return r; };
  float* stats = (float*)(ws + take(256));
  size_t P0 = take(33554432);
  size_t P1 = take(25165824);
  size_t P2 = take(100663296);

  unsigned short* xbf    = (unsigned short*)(ws + P0);
  unsigned short* attnbf = (unsigned short*)(ws + P0);
  unsigned short* hchunk = (unsigned short*)(ws + P0);
  unsigned short* W1bf   = (unsigned short*)(ws + P1);
  float*          spart  = (float*)(ws + P1);
  unsigned short* probs  = (unsigned short*)(ws + P1 + 16777216);
  unsigned short* W2bf   = (unsigned short*)(ws + P1);
  unsigned short* fc_ch  = (unsigned short*)(ws + P1);
  unsigned short* pj_ch  = (unsigned short*)(ws + P1 + 8388608);
  unsigned short* qkv    = (unsigned short*)(ws + P2);
  float*          r12    = (float*)(ws + P2);
  unsigned short* x1bf   = (unsigned short*)(ws + P2 + 67108864);

  zero_f<<<1, 64, 0, stream>>>(stats, 16);
  cvt_f32_bf16<<<16384, 256, 0, stream>>>(x, xbf, 4194304);
  cvt_f32_bf16<<<12288, 256, 0, stream>>>(W1w, W1bf, 3145728);

  // QKV: [8192,2048] @ [6144,2048]^T + W1_b -> qkv bf16 [8192,6144]
  gemm_bt<<<dim3(48, 64, 1), 256, 0, stream>>>(xbf, 2048, 0, 0, W1bf, 2048, 0, 0, 2048, 1, W1b,
                                               nullptr, nullptr, 0, nullptr, qkv, 6144, 0, 0, 0,
                                               nullptr);
  // feature-dim attention scores (split over S into 4) + softmax
  attn_scores<<<dim3(64, 4), 256, 0, stream>>>(qkv, spart);
  softmax_k<<<2048, 256, 0, stream>>>(spart, probs);
  // PV per (b,h): [128,128] @ [2048,128]^T -> attn2d[b, h*128+d, s] bf16
  gemm_bt<<<dim3(16, 1, 64), 256, 0, stream>>>(probs, 128, 262144L, 16384L, qkv + 4096, 6144,
                                               12582912L, 128L, 128, 16, nullptr, nullptr, nullptr,
                                               0, nullptr, attnbf, 2048, 4194304L, 262144L, 0,
                                               nullptr);
  // W2 weights (spart dead; probs at P1+16MB untouched)
  cvt_f32_bf16<<<4096, 256, 0, stream>>>(W2w, W2bf, 1048576);
  // W2 + bias + residual(x fp32) -> r1 fp32, stats[0:2]
  gemm_bt<<<dim3(16, 64, 1), 256, 0, stream>>>(attnbf, 2048, 0, 0, W2bf, 2048, 0, 0, 2048, 1, W2b,
                                               x, nullptr, 0, r12, nullptr, 2048, 0, 0, 0, stats);
  ln_apply<<<16384, 256, 0, stream>>>(r12, stats, ln1w, ln1b, nullptr, x1bf, 4194304);

  // FFN in 4 chunks of DFF=2048: h = gelu(x1 @ fc_ch^T + fcb_ch); r2 += h @ pj_ch^T
  for (int c = 0; c < 4; ++c) {
    cvt_f32_bf16<<<4096, 256, 0, stream>>>(fcw + (size_t)c * 4194304, fc_ch, 1048576);
    cvt_cols<<<4096, 256, 0, stream>>>(pjw, pj_ch, c * 2048);
    gemm_bt<<<dim3(16, 64, 1), 256, 0, stream>>>(x1bf, 2048, 0, 0, fc_ch, 2048, 0, 0, 2048, 1,
                                                 fcb + c * 2048, nullptr, nullptr, 0, nullptr,
                                                 hchunk, 2048, 0, 0, 1, nullptr);
    const int last = (c == 3);
    gemm_bt<<<dim3(16, 64, 1), 256, 0, stream>>>(hchunk, 2048, 0, 0, pj_ch, 2048, 0, 0, 2048, 1,
                                                 last ? pjb : nullptr, nullptr,
                                                 last ? x1bf : nullptr, c > 0, r12, nullptr, 2048,
                                                 0, 0, 0, last ? (stats + 2) : nullptr);
  }
  ln_apply<<<16384, 256, 0, stream>>>(r12, stats + 2, ln2w, ln2b, out, nullptr, 4194304);
}

// Round 5
// 1735.564 us; speedup vs baseline: 1.1698x; 1.0748x over previous
//
#include <hip/hip_runtime.h>
#include <math.h>

typedef float floatx4 __attribute__((ext_vector_type(4)));
typedef __bf16 bf16x8 __attribute__((ext_vector_type(8)));
typedef unsigned short ushortx8 __attribute__((ext_vector_type(8)));
typedef unsigned short ushortx4 __attribute__((ext_vector_type(4)));
typedef unsigned short ushortx2 __attribute__((ext_vector_type(2)));

typedef unsigned int __attribute__((address_space(1))) as1_uint;
typedef unsigned int __attribute__((address_space(3))) as3_uint;

#define DEV static __device__ __forceinline__

DEV unsigned short f32_bf16(float f) {
  unsigned u = __float_as_uint(f);
  u += 0x7FFFu + ((u >> 16) & 1u);
  return (unsigned short)(u >> 16);
}
DEV float bf16_f32(unsigned short h) { return __uint_as_float(((unsigned)h) << 16); }
DEV float gelu_f(float x) {
  float x3 = x * x * x;
  return 0.5f * x * (1.0f + tanhf(0.79788456080286536f * (x + 0.044715f * x3)));
}
DEV void gload16(const void* g, void* l) {
  __builtin_amdgcn_global_load_lds((const as1_uint*)g, (as3_uint*)l, 16, 0, 0);
}
DEV floatx4 mfma16(ushortx8 a, ushortx8 b, floatx4 c) {
  return __builtin_amdgcn_mfma_f32_16x16x32_bf16(
      __builtin_bit_cast(bf16x8, a), __builtin_bit_cast(bf16x8, b), c, 0, 0, 0);
}

// ---------------- small kernels ----------------

__global__ void zero_f(float* p, int n) {
  int i = threadIdx.x;
  if (i < n) p[i] = 0.f;
}

__global__ void cvt_f32_bf16(const float* __restrict__ in, unsigned short* __restrict__ out,
                             long n4) {
  long i = (long)blockIdx.x * blockDim.x + threadIdx.x;
  if (i >= n4) return;
  float4 v = ((const float4*)in)[i];
  ushortx4 o;
  o.x = f32_bf16(v.x); o.y = f32_bf16(v.y); o.z = f32_bf16(v.z); o.w = f32_bf16(v.w);
  ((ushortx4*)out)[i] = o;
}

// out[n*cw + k] = in[n*8192 + cbase + k], n<2048, k<cw ; cwlog4 = log2(cw/4)
__global__ void cvt_cols(const float* __restrict__ in, unsigned short* __restrict__ out,
                         int cbase, int cwlog4, long n4) {
  long i = (long)blockIdx.x * blockDim.x + threadIdx.x;
  if (i >= n4) return;
  int n = (int)(i >> cwlog4);
  int k4 = (int)(i & ((1 << cwlog4) - 1)) << 2;
  float4 v = *(const float4*)&in[(size_t)n * 8192 + cbase + k4];
  ushortx4 o;
  o.x = f32_bf16(v.x); o.y = f32_bf16(v.y); o.z = f32_bf16(v.z); o.w = f32_bf16(v.w);
  *(ushortx4*)&out[((size_t)n << (cwlog4 + 2)) + k4] = o;
}

// one wave per (bh,d) row of 128; scale by 1/sqrt(S), softmax, bf16 out
__global__ __launch_bounds__(256) void softmax_k(const float* __restrict__ sc,
                                                 unsigned short* __restrict__ probs) {
  int r = blockIdx.x * 4 + (threadIdx.x >> 6);
  int lane = threadIdx.x & 63;
  size_t base = (size_t)(r >> 7) * 16384 + (size_t)(r & 127) * 128;
  int e0 = lane * 2;
  float2 p = *(const float2*)&sc[base + e0];
  const float scale = 0.022097086912079608f;  // 1/sqrt(2048)
  float vx = p.x * scale, vy = p.y * scale;
  float m = fmaxf(vx, vy);
#pragma unroll
  for (int off = 32; off; off >>= 1) m = fmaxf(m, __shfl_xor(m, off));
  float ex = expf(vx - m), ey = expf(vy - m);
  float s = ex + ey;
#pragma unroll
  for (int off = 32; off; off >>= 1) s += __shfl_xor(s, off);
  float inv = 1.f / s;
  ushortx2 o;
  o.x = f32_bf16(ex * inv);
  o.y = f32_bf16(ey * inv);
  *(ushortx2*)&probs[base + e0] = o;
}

// global layernorm apply: out = (r - mean)*rstd*w[col] + b[col]
__global__ void ln_apply(const float* __restrict__ r, const float* __restrict__ stats,
                         const float* __restrict__ w, const float* __restrict__ bia,
                         float* __restrict__ outF, unsigned short* __restrict__ outB, long n4) {
  long i = (long)blockIdx.x * blockDim.x + threadIdx.x;
  if (i >= n4) return;
  const double total = 16777216.0;
  double mean = (double)stats[0] / total;
  double var = ((double)stats[1] - total * mean * mean) / (total - 1.0);
  float rstd = (float)(1.0 / sqrt(var + 1e-12));
  float fm = (float)mean;
  int col = (int)((i * 4) & 2047);
  float4 v = ((const float4*)r)[i];
  float4 wv = *(const float4*)&w[col];
  float4 bv = *(const float4*)&bia[col];
  float4 o;
  o.x = (v.x - fm) * rstd * wv.x + bv.x;
  o.y = (v.y - fm) * rstd * wv.y + bv.y;
  o.z = (v.z - fm) * rstd * wv.z + bv.z;
  o.w = (v.w - fm) * rstd * wv.w + bv.w;
  if (outF) ((float4*)outF)[i] = o;
  if (outB) {
    ushortx4 ob;
    ob.x = f32_bf16(o.x); ob.y = f32_bf16(o.y); ob.z = f32_bf16(o.z); ob.w = f32_bf16(o.w);
    ((ushortx4*)outB)[i] = ob;
  }
}

// ---------------- main GEMM: C[M,N] = A[M,K] @ B[N,K]^T, fused epilogue ----------------
// m97 structure: 128x128 tile, BK=64, global_load_lds width-16 staging,
// 4 waves x 4x4 16x16x32 MFMA. C/D layout: col=lane&15, row=quad*4+reg.
// LDS XOR swizzle: physical 16B-slot = logical k-slot ^ (row&7) -> 0 bank conflicts (r4).
// qkv mode (outQT != null): col<2048 -> qT[b,h,d,s]; col<4096 -> kT[b,h,d,s];
// col>=4096 -> V compact [b*2048+s][2048] (outB).
__global__ __launch_bounds__(256) void gemm_bt(
    const unsigned short* __restrict__ A, int lda, long sAo, long sAi,
    const unsigned short* __restrict__ B, int ldb, long sBo, long sBi,
    int K, int innerCnt,
    const float* __restrict__ bias, const float* __restrict__ residF,
    const unsigned short* __restrict__ residB, int accum,
    float* __restrict__ outF, unsigned short* __restrict__ outB,
    unsigned short* __restrict__ outQT,
    int ldc, long sCo, long sCi, int doGelu, float* __restrict__ stats) {
  __shared__ unsigned short As[128 * 64];
  __shared__ unsigned short Bs[128 * 64];
  const int tid = threadIdx.x;
  const int wave = tid >> 6;
  const int lane = tid & 63;
  const int z = blockIdx.z;
  const int zo = z / innerCnt, zi = z % innerCnt;
  const unsigned short* Ab = A + zo * sAo + zi * sAi;
  const unsigned short* Bb = B + zo * sBo + zi * sBi;
  const long coff = zo * sCo + zi * sCi;
  const int m0 = blockIdx.y * 128;
  const int n0 = blockIdx.x * 128;

  const int quad = lane >> 4;
  const int l16 = lane & 15;
  const int wm = (wave & 1) * 64;
  const int wn = (wave >> 1) * 64;
  const int srow = lane >> 3;                          // 0..7 within 8-row group
  const int kofs8 = (((lane & 7) ^ srow) & 7) * 8;     // swizzled k-slot source

  floatx4 acc[4][4];
#pragma unroll
  for (int i = 0; i < 4; i++)
#pragma unroll
    for (int j = 0; j < 4; j++) acc[i][j] = (floatx4){0.f, 0.f, 0.f, 0.f};

  const int nK = K >> 6;
  for (int kt = 0; kt < nK; ++kt) {
    const int k0 = kt << 6;
    __syncthreads();
#pragma unroll
    for (int i = 0; i < 4; ++i) {
      const int rb = wave * 32 + i * 8;
      gload16(Ab + (size_t)(m0 + rb + srow) * lda + k0 + kofs8, &As[rb * 64]);
      gload16(Bb + (size_t)(n0 + rb + srow) * ldb + k0 + kofs8, &Bs[rb * 64]);
    }
    __syncthreads();
#pragma unroll
    for (int kk = 0; kk < 2; ++kk) {
      ushortx8 af[4], bf[4];
      const int swz = (l16 & 7);
#pragma unroll
      for (int i = 0; i < 4; i++)
        af[i] = *(const ushortx8*)&As[(wm + i * 16 + l16) * 64 +
                                      (((kk * 4 + quad) ^ swz) * 8)];
#pragma unroll
      for (int j = 0; j < 4; j++)
        bf[j] = *(const ushortx8*)&Bs[(wn + j * 16 + l16) * 64 +
                                      (((kk * 4 + quad) ^ swz) * 8)];
#pragma unroll
      for (int i = 0; i < 4; i++)
#pragma unroll
        for (int j = 0; j < 4; j++) acc[i][j] = mfma16(af[i], bf[j], acc[i][j]);
    }
  }

  float s1 = 0.f, s2 = 0.f;
#pragma unroll
  for (int i = 0; i < 4; i++) {
#pragma unroll
    for (int j = 0; j < 4; j++) {
      const int col = n0 + wn + j * 16 + l16;
      const float bv = bias ? bias[col] : 0.f;
#pragma unroll
      for (int r = 0; r < 4; r++) {
        const int row = m0 + wm + i * 16 + quad * 4 + r;
        float v = acc[i][j][r] + bv;
        if (doGelu) v = gelu_f(v);
        if (outQT) {
          const int b = row >> 11, s = row & 2047;
          if (col < 4096) {
            unsigned short* tb = outQT + ((col & 2048) ? 16777216u : 0u);
            const int cc = col & 2047;
            tb[((size_t)((b << 4) + (cc >> 7)) * 128 + (cc & 127)) * 2048 + s] = f32_bf16(v);
          } else {
            outB[(size_t)row * 2048 + (col - 4096)] = f32_bf16(v);
          }
          continue;
        }
        const size_t cidx = (size_t)coff + (size_t)row * ldc + col;
        if (residF) v += residF[cidx];
        if (residB) v += bf16_f32(residB[cidx]);
        if (accum) v += outF[cidx];
        if (outF) outF[cidx] = v;
        else outB[cidx] = f32_bf16(v);
        if (stats) { s1 += v; s2 += v * v; }
      }
    }
  }
  if (stats) {
#pragma unroll
    for (int off = 32; off; off >>= 1) {
      s1 += __shfl_down(s1, off);
      s2 += __shfl_down(s2, off);
    }
    if (lane == 0) {
      atomicAdd(&stats[0], s1);
      atomicAdd(&stats[1], s2);
    }
  }
}

// ---------------- launch ----------------
// Workspace (region lifetimes overlapped), base 152 MiB:
//   P0 32MiB: xbf -> attnbf -> hchunk(nc=4)
//   P1 24MiB: W1bf -> {spart(4)+probs(2)} -> W2bf(8) -> {fc_ch(8)+pj_ch(8)} (nc=4)
//   P2 96MiB: {vbf(32)+qT(32)+kT(32)} -> {r12 fp32(64) + x1bf(32)}
//   P3 (optional, ws-adaptive): FFN fc/pj/h for nc=1 (192MiB) or nc=2 (96MiB)

extern "C" void kernel_launch(void* const* d_in, const int* in_sizes, int n_in, void* d_out,
                              int out_size, void* d_ws, size_t ws_size, hipStream_t stream) {
  (void)in_sizes; (void)n_in; (void)out_size;
  const float* x    = (const float*)d_in[0];
  const float* W1w  = (const float*)d_in[1];
  const float* W1b  = (const float*)d_in[2];
  const float* W2w  = (const float*)d_in[3];
  const float* W2b  = (const float*)d_in[4];
  const float* fcw  = (const float*)d_in[5];
  const float* fcb  = (const float*)d_in[6];
  const float* pjw  = (const float*)d_in[7];
  const float* pjb  = (const float*)d_in[8];
  const float* ln1w = (const float*)d_in[9];
  const float* ln1b = (const float*)d_in[10];
  const float* ln2w = (const float*)d_in[11];
  const float* ln2b = (const float*)d_in[12];
  float* out = (float*)d_out;

  char* ws = (char*)d_ws;
  size_t off = 0;
  auto take = [&](size_t b) { size_t r = off; off = (off + b + 255) & ~(size_t)255; return r; };
  float* stats = (float*)(ws + take(256));
  size_t P0 = take(33554432);
  size_t P1 = take(25165824);
  size_t P2 = take(100663296);
  size_t P3 = off;

  unsigned short* xbf    = (unsigned short*)(ws + P0);
  unsigned short* attnbf = (unsigned short*)(ws + P0);
  unsigned short* W1bf   = (unsigned short*)(ws + P1);
  float*          spart  = (float*)(ws + P1);
  unsigned short* probs  = (unsigned short*)(ws + P1 + 4194304);
  unsigned short* W2bf   = (unsigned short*)(ws + P1);
  unsigned short* vbf    = (unsigned short*)(ws + P2);
  unsigned short* qT     = (unsigned short*)(ws + P2 + 33554432);  // kT = qT + 16Mi elems
  float*          r12    = (float*)(ws + P2);
  unsigned short* x1bf   = (unsigned short*)(ws + P2 + 67108864);

  // ws-adaptive FFN chunking
  int nc;
  unsigned short *fc_ch, *pj_ch, *hch;
  if (ws_size >= P3 + 201326592) {  // 192 MiB extra
    nc = 1;
    fc_ch = (unsigned short*)(ws + P3);
    pj_ch = (unsigned short*)(ws + P3 + 33554432);
    hch   = (unsigned short*)(ws + P3 + 67108864);
  } else if (ws_size >= P3 + 100663296) {  // 96 MiB extra
    nc = 2;
    fc_ch = (unsigned short*)(ws + P3);
    pj_ch = (unsigned short*)(ws + P3 + 16777216);
    hch   = (unsigned short*)(ws + P3 + 33554432);
  } else {
    nc = 4;
    fc_ch = (unsigned short*)(ws + P1);
    pj_ch = (unsigned short*)(ws + P1 + 8388608);
    hch   = (unsigned short*)(ws + P0);
  }
  const int cw = 8192 / nc;
  const int cwlog4 = (nc == 1) ? 11 : (nc == 2) ? 10 : 9;
  const long cn4 = (long)cw << 9;  // cw*2048/4

  zero_f<<<1, 64, 0, stream>>>(stats, 16);
  cvt_f32_bf16<<<16384, 256, 0, stream>>>(x, xbf, 4194304);
  cvt_f32_bf16<<<12288, 256, 0, stream>>>(W1w, W1bf, 3145728);

  // QKV: [8192,2048] @ [6144,2048]^T + W1_b -> qT/kT [b,h,128,2048] + vbf [8192,2048]
  gemm_bt<<<dim3(48, 64, 1), 256, 0, stream>>>(xbf, 2048, 0, 0, W1bf, 2048, 0, 0, 2048, 1, W1b,
                                               nullptr, nullptr, 0, nullptr, vbf, qT, 0, 0, 0, 0,
                                               nullptr);
  // scores per (b,h): qT[128,2048] @ kT[128,2048]^T -> spart [bh][128][128] fp32
  gemm_bt<<<dim3(1, 1, 64), 256, 0, stream>>>(qT, 2048, 0, 262144L, qT + 16777216, 2048, 0,
                                              262144L, 2048, 64, nullptr, nullptr, nullptr, 0,
                                              spart, nullptr, nullptr, 128, 0, 16384L, 0, nullptr);
  softmax_k<<<2048, 256, 0, stream>>>(spart, probs);
  // PV per (b,h): P[128,128] @ V[2048,128]^T -> attn2d[b, h*128+d, s] bf16
  gemm_bt<<<dim3(16, 1, 64), 256, 0, stream>>>(probs, 128, 262144L, 16384L, vbf, 2048, 4194304L,
                                               128L, 128, 16, nullptr, nullptr, nullptr, 0,
                                               nullptr, attnbf, nullptr, 2048, 4194304L, 262144L,
                                               0, nullptr);
  cvt_f32_bf16<<<4096, 256, 0, stream>>>(W2w, W2bf, 1048576);
  // W2 + bias + residual(x fp32) -> r1 fp32, stats[0:2]
  gemm_bt<<<dim3(16, 64, 1), 256, 0, stream>>>(attnbf, 2048, 0, 0, W2bf, 2048, 0, 0, 2048, 1, W2b,
                                               x, nullptr, 0, r12, nullptr, nullptr, 2048, 0, 0, 0,
                                               stats);
  ln_apply<<<16384, 256, 0, stream>>>(r12, stats, ln1w, ln1b, nullptr, x1bf, 4194304);

  // FFN in nc chunks of cw: h = gelu(x1 @ fc_ch^T + fcb_ch); r2 (+)= h @ pj_ch^T
  for (int c = 0; c < nc; ++c) {
    cvt_f32_bf16<<<(int)(cn4 / 256), 256, 0, stream>>>(fcw + (size_t)c * cw * 2048, fc_ch, cn4);
    cvt_cols<<<(int)(cn4 / 256), 256, 0, stream>>>(pjw, pj_ch, c * cw, cwlog4, cn4);
    gemm_bt<<<dim3(cw / 128, 64, 1), 256, 0, stream>>>(x1bf, 2048, 0, 0, fc_ch, 2048, 0, 0, 2048,
                                                       1, fcb + c * cw, nullptr, nullptr, 0,
                                                       nullptr, hch, nullptr, cw, 0, 0, 1,
                                                       nullptr);
    const int last = (c == nc - 1);
    gemm_bt<<<dim3(16, 64, 1), 256, 0, stream>>>(hch, cw, 0, 0, pj_ch, cw, 0, 0, cw, 1,
                                                 last ? pjb : nullptr, nullptr,
                                                 last ? x1bf : nullptr, c > 0, r12, nullptr,
                                                 nullptr, 2048, 0, 0, 0,
                                                 last ? (stats + 2) : nullptr);
  }
  ln_apply<<<16384, 256, 0, stream>>>(r12, stats + 2, ln2w, ln2b, out, nullptr, 4194304);
}